// Round 4
// baseline (330.057 us; speedup 1.0000x reference)
//
#include <hip/hip_runtime.h>
#include <hip/hip_bf16.h>
#include <cstdint>

// ---------- types ----------
typedef __attribute__((ext_vector_type(8))) __bf16 bf16x8;
typedef __attribute__((ext_vector_type(4))) float f32x4;
typedef __attribute__((ext_vector_type(8))) unsigned short u16x8;

static __device__ __forceinline__ unsigned short f2b(float f) {
    union { float f; unsigned u; } v; v.f = f;
    unsigned r = v.u + 0x7fffu + ((v.u >> 16) & 1u);   // RNE bf16
    return (unsigned short)(r >> 16);
}
static __device__ __forceinline__ float b2f(unsigned short b) {
    union { unsigned u; float f; } v; v.u = ((unsigned)b) << 16;
    return v.f;
}

// offset field MUST be 0: nonzero imm corrupted the LDS destination (R3 NaN).
// K-advance goes through the pointer as a compile-time constant instead.
#define LL16(g, l) __builtin_amdgcn_global_load_lds( \
    (const __attribute__((address_space(1))) void*)(g), \
    (__attribute__((address_space(3))) void*)(l), 16, 0, 0)

// ---------- fp32 -> bf16 convert (vectorized) ----------
__global__ void conv_f32_bf16(const float* __restrict__ in,
                              unsigned short* __restrict__ out, long n8) {
    long i = (long)blockIdx.x * blockDim.x + threadIdx.x;
    if (i >= n8) return;
    const float4* p = (const float4*)in + i * 2;
    float4 a = p[0], b = p[1];
    u16x8 r;
    r[0] = f2b(a.x); r[1] = f2b(a.y); r[2] = f2b(a.z); r[3] = f2b(a.w);
    r[4] = f2b(b.x); r[5] = f2b(b.y); r[6] = f2b(b.z); r[7] = f2b(b.w);
    *(u16x8*)(out + i * 8) = r;
}

// ---------- W [c][n] f32 -> Wt [n][c] bf16 (LDS tiled transpose) ----------
__global__ void transpose_w(const float* __restrict__ w0,
                            const float* __restrict__ w1,
                            const float* __restrict__ w2,
                            unsigned short* __restrict__ out) {
    __shared__ float tile[32][33];
    int z = blockIdx.z;
    const float* W = (z == 0) ? w0 : (z == 1) ? w1 : w2;
    int n0 = blockIdx.x * 32, c0 = blockIdx.y * 32;
    int tx = threadIdx.x & 31, ty = threadIdx.x >> 5;   // 32 x 8
    #pragma unroll
    for (int i = 0; i < 32; i += 8)
        tile[ty + i][tx] = W[(long)(c0 + ty + i) * 1024 + n0 + tx];
    __syncthreads();
    unsigned short* o = out + (long)z * 1024 * 1024;
    #pragma unroll
    for (int i = 0; i < 32; i += 8)
        o[(long)(n0 + ty + i) * 1024 + c0 + tx] = f2b(tile[tx][ty + i]);
}

// ---------- Vt[b][v][t] /= colsum[b][t] ----------
__global__ void scale_vt(unsigned short* __restrict__ Vt,
                         const float* __restrict__ colsum) {
    long i8 = ((long)blockIdx.x * 256 + threadIdx.x) * 8;
    int b = (int)(i8 >> 21);                 // 1024*2048 = 2^21 per batch
    int rem = (int)(i8 & ((1 << 21) - 1));
    int t = rem & 2047;
    const float* cs = colsum + b * 2048 + t;
    u16x8 v = *(const u16x8*)(Vt + i8);
    u16x8 o;
    #pragma unroll
    for (int j = 0; j < 8; ++j) o[j] = f2b(b2f(v[j]) / cs[j]);
    *(u16x8*)(Vt + i8) = o;
}

// =====================================================================
// 256x256 tile, BK=64, 8-wave (2M x 4N), 8-phase pipelined bf16 GEMM
// C[m][n] = sum_k A[m][k] * Bt[n][k]
// MODE 0: + bias[col], store bf16     (Q/K projection)
// MODE 1: + bias[row], store bf16     (V^T projection)
// MODE 2: e=exp(s/32), store bf16, atomic column sums (scores)
// MODE 3: * mask[row], store f32      (PV -> output)
// =====================================================================

#define BAR() __builtin_amdgcn_s_barrier()
#define WAIT_LGKM0() do { asm volatile("s_waitcnt lgkmcnt(0)" ::: "memory"); \
                          __builtin_amdgcn_sched_barrier(0); } while (0)
#define WAIT_VM2() asm volatile("s_waitcnt vmcnt(2)" ::: "memory")
#define WAIT_VM0() asm volatile("s_waitcnt vmcnt(0)" ::: "memory")

// stage one half-tile (128 rows x 64 k): 2 x global_load_lds(16B)/thread.
// EOFF is a compile-time element offset; source ptrs advance 128 elems/iter.
#define STG_A(buf, h, EOFF) do { \
    LL16(((h) ? sA10 : sA00) + (EOFF), &ldsA[buf][h][dst0]); \
    LL16(((h) ? sA11 : sA01) + (EOFF), &ldsA[buf][h][dst1]); } while (0)
#define STG_B(buf, h, EOFF) do { \
    LL16(((h) ? sB10 : sB00) + (EOFF), &ldsB[buf][h][dst0]); \
    LL16(((h) ? sB11 : sB01) + (EOFF), &ldsB[buf][h][dst1]); } while (0)

// ds-reads: runtime base + compile-time immediate -> ds_read_b128 offset:N
#define LDA(d, mh) do { _Pragma("unroll") for (int fi = 0; fi < 4; ++fi) { \
    af[fi][0] = *(const bf16x8*)&ldsA[d][wr][baA0 + (mh) * 4096 + fi * 1024]; \
    af[fi][1] = *(const bf16x8*)&ldsA[d][wr][baA1 + (mh) * 4096 + fi * 1024]; } } while (0)
#define LDB(d, nh) do { _Pragma("unroll") for (int fj = 0; fj < 2; ++fj) { \
    bf[fj][0] = *(const bf16x8*)&ldsB[d][wcH][baB0 + (nh) * 2048 + fj * 1024]; \
    bf[fj][1] = *(const bf16x8*)&ldsB[d][wcH][baB1 + (nh) * 2048 + fj * 1024]; } } while (0)

#define MMA(mh, nh) do { \
    __builtin_amdgcn_s_setprio(1); \
    _Pragma("unroll") for (int fi = 0; fi < 4; ++fi) \
    _Pragma("unroll") for (int fj = 0; fj < 2; ++fj) { \
        acc[(mh)*4+fi][(nh)*2+fj] = __builtin_amdgcn_mfma_f32_16x16x32_bf16( \
            af[fi][0], bf[fj][0], acc[(mh)*4+fi][(nh)*2+fj], 0, 0, 0); \
        acc[(mh)*4+fi][(nh)*2+fj] = __builtin_amdgcn_mfma_f32_16x16x32_bf16( \
            af[fi][1], bf[fj][1], acc[(mh)*4+fi][(nh)*2+fj], 0, 0, 0); } \
    __builtin_amdgcn_s_setprio(0); } while (0)

template<int MODE>
__global__ __launch_bounds__(512, 2)
void gemm256(const unsigned short* __restrict__ Aall,
             const unsigned short* __restrict__ Ball,
             void* __restrict__ Cv,
             int M, int N, int K, int ldc,
             long aStride, long bStride, long cStride,
             const float* __restrict__ aux, float* __restrict__ colsum) {
    __shared__ unsigned short ldsA[2][2][8192];   // [dbuf][half][128*64]
    __shared__ unsigned short ldsB[2][2][8192];

    // bijective XCD swizzle over the full linear grid (all launches: nwg % 8 == 0)
    const int gx = gridDim.x, gy = gridDim.y;
    const int nxy = gx * gy;
    const int nwg = nxy * gridDim.z;
    const int orig = (blockIdx.z * gy + blockIdx.y) * gx + blockIdx.x;
    const int swz = (orig & 7) * (nwg >> 3) + (orig >> 3);
    const int bz = swz / nxy;
    const int rem = swz - bz * nxy;
    const int by = rem / gx;
    const int bx = rem - by * gx;

    const unsigned short* A  = Aall + (long)bz * aStride;
    const unsigned short* Bt = Ball + (long)bz * bStride;

    const int tid = threadIdx.x;
    const int lane = tid & 63;
    const int w = tid >> 6;                 // 0..7
    const int wr = w >> 2, wc = w & 3;      // 2 x 4 wave grid
    const int wcH = wc >> 1;
    const int lr = lane & 15, lg = lane >> 4;

    const int bm = by * 256, bn = bx * 256;
    const int NI = K >> 7;                  // 2 K-tiles (of 64) per iteration

    // staging source pointers (pre-swizzled: slot s -> row r=s>>3, chunk (s&7)^(r&7))
    const int r0 = tid >> 3;
    const int l0 = (tid & 7) ^ (r0 & 7);
    const unsigned short* sA00 = A  + (long)(bm + r0)       * K + l0 * 8;
    const unsigned short* sA01 = A  + (long)(bm + 64 + r0)  * K + l0 * 8;
    const unsigned short* sA10 = A  + (long)(bm + 128 + r0) * K + l0 * 8;
    const unsigned short* sA11 = A  + (long)(bm + 192 + r0) * K + l0 * 8;
    const unsigned short* sB00 = Bt + (long)(bn + r0)       * K + l0 * 8;
    const unsigned short* sB01 = Bt + (long)(bn + 64 + r0)  * K + l0 * 8;
    const unsigned short* sB10 = Bt + (long)(bn + 128 + r0) * K + l0 * 8;
    const unsigned short* sB11 = Bt + (long)(bn + 192 + r0) * K + l0 * 8;
    const int dst0 = w * 512;               // wave-uniform LDS dest (elements)
    const int dst1 = 4096 + w * 512;

    // LDS read bases (elements); reads add compile-time immediates only
    const int cx0 = (lg ^ (lr & 7)) * 8;
    const int cx1 = ((4 + lg) ^ (lr & 7)) * 8;
    const int baA0 = lr * 64 + cx0;
    const int baA1 = lr * 64 + cx1;
    const int baB0 = ((wc & 1) * 64 + lr) * 64 + cx0;
    const int baB1 = ((wc & 1) * 64 + lr) * 64 + cx1;

    bf16x8 af[4][2], bf[2][2];
    f32x4 acc[8][4] = {};

    // prologue: stage tile0 fully + tile1.B-half0; wait all but last half-tile
    STG_B(0, 0, 0); STG_B(0, 1, 0); STG_A(0, 0, 0); STG_A(0, 1, 0);
    STG_B(1, 0, 64);
    WAIT_VM2();
    BAR();

    for (int i = 0; i < NI; ++i) {
        const bool more = (i + 1 < NI);
        // ---- K-tile 2i (buf 0): phases (m0,n0)(m1,n0)(m1,n1)(m0,n1) ----
        LDA(0, 0); LDB(0, 0); STG_B(1, 1, 64);
        BAR(); WAIT_LGKM0(); MMA(0, 0); BAR();

        LDA(0, 1); STG_A(1, 0, 64);
        BAR(); WAIT_LGKM0(); MMA(1, 0); BAR();

        LDB(0, 1); STG_A(1, 1, 64);
        BAR(); WAIT_LGKM0(); MMA(1, 1); BAR();

        LDA(0, 0); if (more) STG_B(0, 0, 128);
        BAR(); WAIT_LGKM0(); MMA(0, 1);
        if (more) { WAIT_VM2(); } else { WAIT_VM0(); }   // race-safe tail
        BAR();

        // ---- K-tile 2i+1 (buf 1) ----
        LDA(1, 0); LDB(1, 0); if (more) STG_B(0, 1, 128);
        BAR(); WAIT_LGKM0(); MMA(0, 0); BAR();

        LDA(1, 1); if (more) STG_A(0, 0, 128);
        BAR(); WAIT_LGKM0(); MMA(1, 0); BAR();

        LDB(1, 1); if (more) STG_A(0, 1, 128);
        BAR(); WAIT_LGKM0(); MMA(1, 1); BAR();

        LDA(1, 0); if (more) STG_B(1, 0, 192);
        BAR(); WAIT_LGKM0(); MMA(0, 1);
        WAIT_VM2();                                      // last iter: queue empty
        BAR();

        sA00 += 128; sA01 += 128; sA10 += 128; sA11 += 128;
        sB00 += 128; sB01 += 128; sB10 += 128; sB11 += 128;
    }

    // ---- epilogue ----
    const int row0 = bm + wr * 128;
    const int col0 = bn + wc * 64;

    if (MODE == 0) {
        unsigned short* C = (unsigned short*)Cv + (long)bz * cStride;
        #pragma unroll
        for (int nj = 0; nj < 4; ++nj) {
            int col = col0 + nj * 16 + lr;
            float bias = aux[col];
            #pragma unroll
            for (int mi = 0; mi < 8; ++mi) {
                int row = row0 + mi * 16 + lg * 4;
                #pragma unroll
                for (int r = 0; r < 4; ++r)
                    C[(long)(row + r) * ldc + col] = f2b(acc[mi][nj][r] + bias);
            }
        }
    } else if (MODE == 1) {
        unsigned short* C = (unsigned short*)Cv + (long)bz * cStride;
        #pragma unroll
        for (int mi = 0; mi < 8; ++mi) {
            #pragma unroll
            for (int r = 0; r < 4; ++r) {
                int row = row0 + mi * 16 + lg * 4 + r;
                float bias = aux[row];
                #pragma unroll
                for (int nj = 0; nj < 4; ++nj) {
                    int col = col0 + nj * 16 + lr;
                    C[(long)row * ldc + col] = f2b(acc[mi][nj][r] + bias);
                }
            }
        }
    } else if (MODE == 2) {
        unsigned short* C = (unsigned short*)Cv + (long)bz * cStride;
        float* cs = colsum + (long)bz * 2048;
        #pragma unroll
        for (int nj = 0; nj < 4; ++nj) {
            int col = col0 + nj * 16 + lr;
            float psum = 0.f;
            #pragma unroll
            for (int mi = 0; mi < 8; ++mi) {
                int row = row0 + mi * 16 + lg * 4;
                #pragma unroll
                for (int r = 0; r < 4; ++r) {
                    float e = __expf(acc[mi][nj][r] * 0.03125f);
                    psum += e;
                    C[(long)(row + r) * ldc + col] = f2b(e);
                }
            }
            psum += __shfl_xor(psum, 16);
            psum += __shfl_xor(psum, 32);
            if (lg == 0) atomicAdd(&cs[col], psum);
        }
    } else {  // MODE 3
        float* C = (float*)Cv + (long)bz * cStride;
        const float* mk = aux + (long)bz * 2048;
        #pragma unroll
        for (int mi = 0; mi < 8; ++mi) {
            #pragma unroll
            for (int r = 0; r < 4; ++r) {
                int row = row0 + mi * 16 + lg * 4 + r;
                float m = mk[row];
                #pragma unroll
                for (int nj = 0; nj < 4; ++nj) {
                    int col = col0 + nj * 16 + lr;
                    C[(long)row * ldc + col] = acc[mi][nj][r] * m;
                }
            }
        }
    }
}

// ---------- host ----------
extern "C" void kernel_launch(void* const* d_in, const int* in_sizes, int n_in,
                              void* d_out, int out_size, void* d_ws, size_t ws_size,
                              hipStream_t stream) {
    const float* x    = (const float*)d_in[0];   // [8,2048,1024]
    const float* mask = (const float*)d_in[1];   // [8,2048,1]
    const float* Wq   = (const float*)d_in[2];
    const float* bq   = (const float*)d_in[3];
    const float* Wk   = (const float*)d_in[4];
    const float* bk   = (const float*)d_in[5];
    const float* Wv   = (const float*)d_in[6];
    const float* bv   = (const float*)d_in[7];
    float* out = (float*)d_out;

    const long MT = 16384;           // B*T
    unsigned short* Xb = (unsigned short*)d_ws;        // [16384][1024]
    unsigned short* Wt = Xb + MT * 1024;               // 3x [1024][1024] (n-major)
    unsigned short* Q  = Wt + 3L * 1024 * 1024;        // [16384][1024]
    unsigned short* Kk = Q  + MT * 1024;               // [16384][1024]
    unsigned short* Vt = Kk + MT * 1024;               // [8][1024 v][2048 t]
    unsigned short* E  = Vt + 8L * 1024 * 2048;        // [8][2048 q][2048 t]
    float* colsum = (float*)(E + 8L * 2048 * 2048);    // [8][2048]
    size_t need = (size_t)((char*)(colsum + 8 * 2048) - (char*)d_ws);
    if (ws_size < need) return;

    // 1. input -> bf16
    conv_f32_bf16<<<(MT * 1024) / 8 / 256, 256, 0, stream>>>(x, Xb, (MT * 1024) / 8);
    // 2. weights -> bf16 transposed [n][c]
    transpose_w<<<dim3(32, 32, 3), 256, 0, stream>>>(Wq, Wk, Wv, Wt);
    // 3. Q = X Wq + bq ; K = X Wk + bk   (bf16 out)  grid 4x64 = 256 wgs
    gemm256<0><<<dim3(4, 64, 1), 512, 0, stream>>>(
        Xb, Wt, Q, 16384, 1024, 1024, 1024, 0, 0, 0, bq, nullptr);
    gemm256<0><<<dim3(4, 64, 1), 512, 0, stream>>>(
        Xb, Wt + 1048576, Kk, 16384, 1024, 1024, 1024, 0, 0, 0, bk, nullptr);
    // 4. Vt[b] = (X_b Wv + bv)^T -> [v][t]  (A = Wv^T, Bt = X_b)  grid 8x4x8
    gemm256<1><<<dim3(8, 4, 8), 512, 0, stream>>>(
        Wt + 2097152, Xb, Vt, 1024, 2048, 1024, 2048,
        0, 2048L * 1024, 1024L * 2048, bv, nullptr);
    // 5. colsum = 0 ; E = exp(Q K^T / 32) with atomic column sums  grid 8x8x8
    hipMemsetAsync(colsum, 0, 8 * 2048 * sizeof(float), stream);
    gemm256<2><<<dim3(8, 8, 8), 512, 0, stream>>>(
        Q, Kk, E, 2048, 2048, 1024, 2048,
        2048L * 1024, 2048L * 1024, 2048L * 2048, nullptr, colsum);
    // 6. Vt /= colsum (per t)
    scale_vt<<<8192, 256, 0, stream>>>(Vt, colsum);
    // 7. out[b] = E_b @ Vn_b^T * mask   grid 4x8x8
    gemm256<3><<<dim3(4, 8, 8), 512, 0, stream>>>(
        E, Vt, out, 2048, 1024, 2048, 1024,
        2048L * 2048, 1024L * 2048, 2048L * 1024, mask, nullptr);
}

// Round 5
// 302.052 us; speedup vs baseline: 1.0927x; 1.0927x over previous
//
#include <hip/hip_runtime.h>
#include <hip/hip_bf16.h>
#include <cstdint>

// ---------- types ----------
typedef __attribute__((ext_vector_type(8))) __bf16 bf16x8;
typedef __attribute__((ext_vector_type(4))) float f32x4;
typedef __attribute__((ext_vector_type(8))) unsigned short u16x8;

static __device__ __forceinline__ unsigned short f2b(float f) {
    union { float f; unsigned u; } v; v.f = f;
    unsigned r = v.u + 0x7fffu + ((v.u >> 16) & 1u);   // RNE bf16
    return (unsigned short)(r >> 16);
}
static __device__ __forceinline__ float b2f(unsigned short b) {
    union { unsigned u; float f; } v; v.u = ((unsigned)b) << 16;
    return v.f;
}

// offset field MUST be 0 on gfx950 (nonzero imm corrupted LDS dest -> R3 NaN).
#define LL16(g, l) __builtin_amdgcn_global_load_lds( \
    (const __attribute__((address_space(1))) void*)(g), \
    (__attribute__((address_space(3))) void*)(l), 16, 0, 0)

// ---------- fp32 -> bf16 convert (vectorized) ----------
__global__ void conv_f32_bf16(const float* __restrict__ in,
                              unsigned short* __restrict__ out, long n8) {
    long i = (long)blockIdx.x * blockDim.x + threadIdx.x;
    if (i >= n8) return;
    const float4* p = (const float4*)in + i * 2;
    float4 a = p[0], b = p[1];
    u16x8 r;
    r[0] = f2b(a.x); r[1] = f2b(a.y); r[2] = f2b(a.z); r[3] = f2b(a.w);
    r[4] = f2b(b.x); r[5] = f2b(b.y); r[6] = f2b(b.z); r[7] = f2b(b.w);
    *(u16x8*)(out + i * 8) = r;
}

// ---------- W [c][n] f32 -> Wt [n][c] bf16 (LDS tiled transpose) ----------
__global__ void transpose_w(const float* __restrict__ w0,
                            const float* __restrict__ w1,
                            const float* __restrict__ w2,
                            unsigned short* __restrict__ out) {
    __shared__ float tile[32][33];
    int z = blockIdx.z;
    const float* W = (z == 0) ? w0 : (z == 1) ? w1 : w2;
    int n0 = blockIdx.x * 32, c0 = blockIdx.y * 32;
    int tx = threadIdx.x & 31, ty = threadIdx.x >> 5;   // 32 x 8
    #pragma unroll
    for (int i = 0; i < 32; i += 8)
        tile[ty + i][tx] = W[(long)(c0 + ty + i) * 1024 + n0 + tx];
    __syncthreads();
    unsigned short* o = out + (long)z * 1024 * 1024;
    #pragma unroll
    for (int i = 0; i < 32; i += 8)
        o[(long)(n0 + ty + i) * 1024 + c0 + tx] = f2b(tile[tx][ty + i]);
}

// ---------- Vt[b][v][t] /= colsum[b][t] ----------
__global__ void scale_vt(unsigned short* __restrict__ Vt,
                         const float* __restrict__ colsum) {
    long i8 = ((long)blockIdx.x * 256 + threadIdx.x) * 8;
    int b = (int)(i8 >> 21);                 // 1024*2048 = 2^21 per batch
    int rem = (int)(i8 & ((1 << 21) - 1));
    int t = rem & 2047;
    const float* cs = colsum + b * 2048 + t;
    u16x8 v = *(const u16x8*)(Vt + i8);
    u16x8 o;
    #pragma unroll
    for (int j = 0; j < 8; ++j) o[j] = f2b(b2f(v[j]) / cs[j]);
    *(u16x8*)(Vt + i8) = o;
}

// =====================================================================
// 256x256 tile, BK=64, 8-wave (2M x 4N), 8-phase pipelined bf16 GEMM
// Phase order per K-tile: (m0n0)(m0n1)(m1n1)(m1n0) with bfA/bfB frag
// sets -> phase 4 has zero ds_reads; 24 b128/wave/K-tile.
// Epilogue: LDS repack -> fully coalesced 16B/lane global stores.
// MODE 0: + bias[col], bf16   MODE 1: + bias[row], bf16
// MODE 2: exp(s/32), bf16 + atomic colsum   MODE 3: * mask[row], f32
// =====================================================================

#define BAR() __builtin_amdgcn_s_barrier()
#define SCHED0() __builtin_amdgcn_sched_barrier(0)
#define WAIT_LGKM0() do { asm volatile("s_waitcnt lgkmcnt(0)" ::: "memory"); \
                          __builtin_amdgcn_sched_barrier(0); } while (0)
#define WAIT_VM2() asm volatile("s_waitcnt vmcnt(2)" ::: "memory")
#define WAIT_VM0() asm volatile("s_waitcnt vmcnt(0)" ::: "memory")

#define STG_A(buf, h, EOFF) do { \
    LL16(((h) ? sA10 : sA00) + (EOFF), ldsA + (buf)*16384 + (h)*8192 + dst0); \
    LL16(((h) ? sA11 : sA01) + (EOFF), ldsA + (buf)*16384 + (h)*8192 + dst1); } while (0)
#define STG_B(buf, h, EOFF) do { \
    LL16(((h) ? sB10 : sB00) + (EOFF), ldsB + (buf)*16384 + (h)*8192 + dst0); \
    LL16(((h) ? sB11 : sB01) + (EOFF), ldsB + (buf)*16384 + (h)*8192 + dst1); } while (0)

#define LDA(d, mh) do { _Pragma("unroll") for (int fi = 0; fi < 4; ++fi) { \
    af[fi][0] = *(const bf16x8*)(ldsA + (d)*16384 + wr*8192 + baA0 + (mh)*4096 + fi*1024); \
    af[fi][1] = *(const bf16x8*)(ldsA + (d)*16384 + wr*8192 + baA1 + (mh)*4096 + fi*1024); } } while (0)
#define LDB(d, nh, BF) do { _Pragma("unroll") for (int fj = 0; fj < 2; ++fj) { \
    BF[fj][0] = *(const bf16x8*)(ldsB + (d)*16384 + wcH*8192 + baB0 + (nh)*2048 + fj*1024); \
    BF[fj][1] = *(const bf16x8*)(ldsB + (d)*16384 + wcH*8192 + baB1 + (nh)*2048 + fj*1024); } } while (0)

#define MMA(mh, nh, BF) do { \
    __builtin_amdgcn_s_setprio(1); \
    _Pragma("unroll") for (int fi = 0; fi < 4; ++fi) \
    _Pragma("unroll") for (int fj = 0; fj < 2; ++fj) { \
        acc[(mh)*4+fi][(nh)*2+fj] = __builtin_amdgcn_mfma_f32_16x16x32_bf16( \
            af[fi][0], BF[fj][0], acc[(mh)*4+fi][(nh)*2+fj], 0, 0, 0); \
        acc[(mh)*4+fi][(nh)*2+fj] = __builtin_amdgcn_mfma_f32_16x16x32_bf16( \
            af[fi][1], BF[fj][1], acc[(mh)*4+fi][(nh)*2+fj], 0, 0, 0); } \
    __builtin_amdgcn_s_setprio(0); } while (0)

template<int MODE>
__global__ __launch_bounds__(512, 2)
void gemm256(const unsigned short* __restrict__ Aall,
             const unsigned short* __restrict__ Ball,
             void* __restrict__ Cv,
             int M, int N, int K, int ldc,
             long aStride, long bStride, long cStride,
             const float* __restrict__ aux, float* __restrict__ colsum) {
    __shared__ unsigned short lds[65536];            // 128 KiB
    unsigned short* const ldsA = lds;                // [2][2][8192]
    unsigned short* const ldsB = lds + 32768;        // [2][2][8192]

    // bijective XCD swizzle over the full linear grid (all launches: nwg % 8 == 0)
    const int gx = gridDim.x, gy = gridDim.y;
    const int nxy = gx * gy;
    const int nwg = nxy * gridDim.z;
    const int orig = (blockIdx.z * gy + blockIdx.y) * gx + blockIdx.x;
    const int swz = (orig & 7) * (nwg >> 3) + (orig >> 3);
    const int bz = swz / nxy;
    const int rem = swz - bz * nxy;
    const int by = rem / gx;
    const int bx = rem - by * gx;

    const unsigned short* A  = Aall + (long)bz * aStride;
    const unsigned short* Bt = Ball + (long)bz * bStride;

    const int tid = threadIdx.x;
    const int lane = tid & 63;
    const int w = tid >> 6;                 // 0..7
    const int wr = w >> 2, wc = w & 3;      // 2 x 4 wave grid
    const int wcH = wc >> 1;
    const int lr = lane & 15, lg = lane >> 4;

    const int bm = by * 256, bn = bx * 256;
    const int NI = K >> 7;                  // 2 K-tiles (of 64) per iteration

    // staging source pointers (pre-swizzled: slot s -> row r=s>>3, chunk (s&7)^(r&7))
    const int r0 = tid >> 3;
    const int l0 = (tid & 7) ^ (r0 & 7);
    const unsigned short* sA00 = A  + (long)(bm + r0)       * K + l0 * 8;
    const unsigned short* sA01 = A  + (long)(bm + 64 + r0)  * K + l0 * 8;
    const unsigned short* sA10 = A  + (long)(bm + 128 + r0) * K + l0 * 8;
    const unsigned short* sA11 = A  + (long)(bm + 192 + r0) * K + l0 * 8;
    const unsigned short* sB00 = Bt + (long)(bn + r0)       * K + l0 * 8;
    const unsigned short* sB01 = Bt + (long)(bn + 64 + r0)  * K + l0 * 8;
    const unsigned short* sB10 = Bt + (long)(bn + 128 + r0) * K + l0 * 8;
    const unsigned short* sB11 = Bt + (long)(bn + 192 + r0) * K + l0 * 8;
    const int dst0 = w * 512;               // wave-uniform LDS dest (elements)
    const int dst1 = 4096 + w * 512;

    // LDS read bases (elements); reads add compile-time immediates only
    const int cx0 = (lg ^ (lr & 7)) * 8;
    const int cx1 = ((4 + lg) ^ (lr & 7)) * 8;
    const int baA0 = lr * 64 + cx0;
    const int baA1 = lr * 64 + cx1;
    const int baB0 = ((wc & 1) * 64 + lr) * 64 + cx0;
    const int baB1 = ((wc & 1) * 64 + lr) * 64 + cx1;

    bf16x8 af[4][2], bfA[2][2], bfB[2][2];
    f32x4 acc[8][4] = {};

    // prologue: stage tile0 fully + tile1.B-half0; wait all but last half-tile
    STG_B(0, 0, 0); STG_B(0, 1, 0); STG_A(0, 0, 0); STG_A(0, 1, 0);
    STG_B(1, 0, 64);
    WAIT_VM2();
    BAR();

    for (int i = 0; i < NI; ++i) {
        const bool more = (i + 1 < NI);
        // ---- K-tile 2i (buf 0): (m0n0)(m0n1)(m1n1)(m1n0) ----
        LDA(0, 0); LDB(0, 0, bfA); STG_B(1, 1, 64);
        BAR(); WAIT_LGKM0(); MMA(0, 0, bfA); BAR();

        LDB(0, 1, bfB); STG_A(1, 0, 64);
        BAR(); WAIT_LGKM0(); MMA(0, 1, bfB); BAR();

        LDA(0, 1); STG_A(1, 1, 64);
        BAR(); WAIT_LGKM0(); MMA(1, 1, bfB); BAR();

        if (more) STG_B(0, 0, 128);
        BAR(); SCHED0(); MMA(1, 0, bfA);
        if (more) { WAIT_VM2(); } else { WAIT_VM0(); }   // race-safe tail
        BAR();

        // ---- K-tile 2i+1 (buf 1) ----
        LDA(1, 0); LDB(1, 0, bfA); if (more) STG_B(0, 1, 128);
        BAR(); WAIT_LGKM0(); MMA(0, 0, bfA); BAR();

        LDB(1, 1, bfB); if (more) STG_A(0, 0, 128);
        BAR(); WAIT_LGKM0(); MMA(0, 1, bfB); BAR();

        LDA(1, 1); if (more) STG_A(0, 1, 128);
        BAR(); WAIT_LGKM0(); MMA(1, 1, bfB); BAR();

        if (more) STG_B(1, 0, 192);
        BAR(); SCHED0(); MMA(1, 0, bfA);
        WAIT_VM2();                                      // last iter: queue empty
        BAR();

        sA00 += 128; sA01 += 128; sA10 += 128; sA11 += 128;
        sB00 += 128; sB01 += 128; sB10 += 128; sB11 += 128;
    }

    // ---- epilogue: repack through LDS for coalesced stores ----
    const int rloc0 = wr * 128;             // row within 256-tile
    const int cloc0 = wc * 64;              // col within 256-tile

    if (MODE != 3) {
        unsigned short* C = (unsigned short*)Cv + (long)bz * cStride;
        float* cs = colsum + (long)bz * 2048;
        #pragma unroll
        for (int nj = 0; nj < 4; ++nj) {
            int cl = cloc0 + nj * 16 + lr;                 // col in tile
            int cb = cl >> 3, cIn = cl & 7;
            float colB = (MODE == 0) ? aux[bn + cl] : 0.f;
            float psum = 0.f;
            #pragma unroll
            for (int mi = 0; mi < 8; ++mi) {
                #pragma unroll
                for (int r = 0; r < 4; ++r) {
                    int rl = rloc0 + mi * 16 + lg * 4 + r; // row in tile
                    float v = acc[mi][nj][r];
                    if (MODE == 0) v += colB;
                    else if (MODE == 1) v += aux[bm + rl];
                    else { v = __expf(v * 0.03125f); psum += v; }
                    int ch = cb ^ ((rl & 7) << 2);
                    lds[rl * 256 + ch * 8 + cIn] = f2b(v);
                }
            }
            if (MODE == 2) {
                psum += __shfl_xor(psum, 16);
                psum += __shfl_xor(psum, 32);
                if (lg == 0) atomicAdd(&cs[bn + cl], psum);
            }
        }
        BAR();
        #pragma unroll
        for (int it = 0; it < 16; ++it) {
            int lin = it * 512 + tid;       // 16B chunks; 8192 total
            int row = lin >> 5;             // 256 rows x 32 chunks
            int c = lin & 31;
            u16x8 v = *(const u16x8*)&lds[row * 256 + ((c ^ ((row & 7) << 2)) << 3)];
            *(u16x8*)&C[(long)(bm + row) * ldc + bn + c * 8] = v;
        }
    } else {  // MODE 3: f32, two half-tiles of 128 rows
        float* C = (float*)Cv + (long)bz * cStride;
        const float* mk = aux + (long)bz * 2048;
        float* ft = (float*)lds;            // [128][256] f32
        #pragma unroll
        for (int h = 0; h < 2; ++h) {
            if (h) BAR();                   // previous copy done before overwrite
            if (wr == h) {
                #pragma unroll
                for (int nj = 0; nj < 4; ++nj) {
                    int cl = cloc0 + nj * 16 + lr;
                    int cf = cl >> 2, cIn = cl & 3;
                    #pragma unroll
                    for (int mi = 0; mi < 8; ++mi) {
                        #pragma unroll
                        for (int r = 0; r < 4; ++r) {
                            int rl = mi * 16 + lg * 4 + r;     // 0..127
                            float m = mk[bm + h * 128 + rl];
                            int cfs = cf ^ ((rl & 7) << 2);
                            ft[rl * 256 + cfs * 4 + cIn] = acc[mi][nj][r] * m;
                        }
                    }
                }
            }
            BAR();
            #pragma unroll
            for (int it = 0; it < 16; ++it) {
                int lin = it * 512 + tid;   // float4 chunks; 8192 total
                int row = lin >> 6;         // 128 rows x 64 chunks
                int cf = lin & 63;
                float4 v = *(const float4*)&ft[row * 256 + ((cf ^ ((row & 7) << 2)) << 2)];
                *(float4*)&C[(long)(bm + h * 128 + row) * ldc + bn + cf * 4] = v;
            }
        }
    }
}

// ---------- host ----------
extern "C" void kernel_launch(void* const* d_in, const int* in_sizes, int n_in,
                              void* d_out, int out_size, void* d_ws, size_t ws_size,
                              hipStream_t stream) {
    const float* x    = (const float*)d_in[0];   // [8,2048,1024]
    const float* mask = (const float*)d_in[1];   // [8,2048,1]
    const float* Wq   = (const float*)d_in[2];
    const float* bq   = (const float*)d_in[3];
    const float* Wk   = (const float*)d_in[4];
    const float* bk   = (const float*)d_in[5];
    const float* Wv   = (const float*)d_in[6];
    const float* bv   = (const float*)d_in[7];
    float* out = (float*)d_out;

    const long MT = 16384;           // B*T
    unsigned short* Xb = (unsigned short*)d_ws;        // [16384][1024]
    unsigned short* Wt = Xb + MT * 1024;               // 3x [1024][1024] (n-major)
    unsigned short* Q  = Wt + 3L * 1024 * 1024;        // [16384][1024]
    unsigned short* Kk = Q  + MT * 1024;               // [16384][1024]
    unsigned short* Vt = Kk + MT * 1024;               // [8][1024 v][2048 t]
    unsigned short* E  = Vt + 8L * 1024 * 2048;        // [8][2048 q][2048 t]
    float* colsum = (float*)(E + 8L * 2048 * 2048);    // [8][2048]
    size_t need = (size_t)((char*)(colsum + 8 * 2048) - (char*)d_ws);
    if (ws_size < need) return;

    // 1. input -> bf16
    conv_f32_bf16<<<(MT * 1024) / 8 / 256, 256, 0, stream>>>(x, Xb, (MT * 1024) / 8);
    // 2. weights -> bf16 transposed [n][c]
    transpose_w<<<dim3(32, 32, 3), 256, 0, stream>>>(Wq, Wk, Wv, Wt);
    // 3. Q = X Wq + bq ; K = X Wk + bk   (bf16 out)  grid 4x64 = 256 wgs
    gemm256<0><<<dim3(4, 64, 1), 512, 0, stream>>>(
        Xb, Wt, Q, 16384, 1024, 1024, 1024, 0, 0, 0, bq, nullptr);
    gemm256<0><<<dim3(4, 64, 1), 512, 0, stream>>>(
        Xb, Wt + 1048576, Kk, 16384, 1024, 1024, 1024, 0, 0, 0, bk, nullptr);
    // 4. Vt[b] = (X_b Wv + bv)^T -> [v][t]  (A = Wv^T, Bt = X_b)  grid 8x4x8
    gemm256<1><<<dim3(8, 4, 8), 512, 0, stream>>>(
        Wt + 2097152, Xb, Vt, 1024, 2048, 1024, 2048,
        0, 2048L * 1024, 1024L * 2048, bv, nullptr);
    // 5. colsum = 0 ; E = exp(Q K^T / 32) with atomic column sums  grid 8x8x8
    hipMemsetAsync(colsum, 0, 8 * 2048 * sizeof(float), stream);
    gemm256<2><<<dim3(8, 8, 8), 512, 0, stream>>>(
        Q, Kk, E, 2048, 2048, 1024, 2048,
        2048L * 1024, 2048L * 1024, 2048L * 2048, nullptr, colsum);
    // 6. Vt /= colsum (per t)
    scale_vt<<<8192, 256, 0, stream>>>(Vt, colsum);
    // 7. out[b] = E_b @ Vn_b^T * mask   grid 4x8x8
    gemm256<3><<<dim3(4, 8, 8), 512, 0, stream>>>(
        E, Vt, out, 2048, 1024, 2048, 1024,
        2048L * 2048, 1024L * 2048, 2048L * 1024, mask, nullptr);
}